// Round 4
// baseline (392.295 us; speedup 1.0000x reference)
//
#include <hip/hip_runtime.h>
#include <math.h>

typedef float v4f __attribute__((ext_vector_type(4)));

#define N_TRAIN 400000
#define DIMS    27
#define BQ      512
#define NCLS    11
#define KNN     3
#define G1      1024   // pass-1 blocks
#define PPB     391    // ceil(N_TRAIN / G1)
#define T1      256    // pass-1 threads per block (4 waves)
#define SPTS    128    // points staged in LDS per iteration
#define T2      256    // pass-2 threads
#define SB      512    // k_scale blocks
#define SROWS   128    // k_scale rows per tile

// ---------------- scale = max(|train|, axis=0), coalesced via LDS staging ----------------
__global__ __launch_bounds__(256) void k_scale(const float* __restrict__ train,
                                               unsigned* __restrict__ scale_u) {
    __shared__ float st[SROWS * DIMS];
    __shared__ float sp[243];           // 27 cols x 9 row-groups
    int tid = threadIdx.x;
    int rpb = (N_TRAIN + SB - 1) / SB;  // 782 rows per block
    int r0 = blockIdx.x * rpb;
    int r1 = min(r0 + rpb, N_TRAIN);
    int c  = tid % DIMS;
    int rr = tid / DIMS;
    float m = 0.f;
    for (int base = r0; base < r1; base += SROWS) {
        int cnt = min(SROWS, r1 - base);
        int tot = cnt * DIMS;
        const float* src = train + (size_t)base * DIMS;
        for (int i = tid; i < tot; i += 256) st[i] = src[i];   // flat coalesced
        __syncthreads();
        if (tid < 243) {
            for (int r = rr; r < cnt; r += 9)
                m = fmaxf(m, fabsf(st[r * DIMS + c]));
        }
        __syncthreads();
    }
    if (tid < 243) sp[tid] = m;
    __syncthreads();
    if (tid < DIMS) {
        float v = 0.f;
#pragma unroll
        for (int g = 0; g < 9; ++g) v = fmaxf(v, sp[g * DIMS + tid]);
        atomicMax(&scale_u[tid], __float_as_uint(v)); // values >= 0: uint order == float order
    }
}

// elementwise fma on v4f (explicit fmaf so contraction is guaranteed)
#define FMA4(ACC, Q, X) \
    ACC.x = fmaf((Q).x, (X).x, ACC.x); \
    ACC.y = fmaf((Q).y, (X).y, ACC.y); \
    ACC.z = fmaf((Q).z, (X).z, ACC.z); \
    ACC.w = fmaf((Q).w, (X).w, ACC.w)

// strict-< top3 insert (earlier/lower index wins ties), named-scalar state
#define TOP3(D2, GI, B0, B1, B2, I0, I1, I2) \
    if ((D2) < B2) { \
        if ((D2) < B1) { \
            B2 = B1; I2 = I1; \
            if ((D2) < B0) { B1 = B0; I1 = I0; B0 = (D2); I0 = (GI); } \
            else { B1 = (D2); I1 = (GI); } \
        } else { B2 = (D2); I2 = (GI); } \
    }

// load query qq, scale it, pack into 7 named v4f (pad slot 27 = 0) + its norm
#define LOADQ(QQ, Q0, Q1, Q2, Q3, Q4, Q5, Q6, QN) do { \
        const float* r_ = query + (size_t)(QQ) * DIMS; \
        float t_[28]; \
        _Pragma("unroll") \
        for (int d_ = 0; d_ < DIMS; ++d_) t_[d_] = r_[d_] * s_inv[d_]; \
        t_[27] = 0.f; \
        float s2_ = 0.f; \
        _Pragma("unroll") \
        for (int d_ = 0; d_ < DIMS; ++d_) s2_ = fmaf(t_[d_], t_[d_], s2_); \
        QN = s2_; \
        Q0 = (v4f){t_[0],  t_[1],  t_[2],  t_[3]}; \
        Q1 = (v4f){t_[4],  t_[5],  t_[6],  t_[7]}; \
        Q2 = (v4f){t_[8],  t_[9],  t_[10], t_[11]}; \
        Q3 = (v4f){t_[12], t_[13], t_[14], t_[15]}; \
        Q4 = (v4f){t_[16], t_[17], t_[18], t_[19]}; \
        Q5 = (v4f){t_[20], t_[21], t_[22], t_[23]}; \
        Q6 = (v4f){t_[24], t_[25], t_[26], 0.f}; \
    } while (0)

// ---------------- pass 1: per-chunk top-3 per query ----------------
// amdgpu_waves_per_eu(2,2): pin occupancy to 2 waves/EU -> 256-VGPR budget,
// removing the allocator's incentive to spill the query registers for occupancy.
__global__ __attribute__((amdgpu_flat_work_group_size(T1, T1)))
__attribute__((amdgpu_waves_per_eu(2, 2)))
void k_pass1(const float* __restrict__ train,
             const float* __restrict__ query,
             const unsigned* __restrict__ scale_u,
             float* __restrict__ cand_d,
             int* __restrict__ cand_i) {
    __shared__ float s_inv[32];
    __shared__ float s_pts[SPTS * 28]; // [point][0..26]=scaled dims, [27]=||x||^2
    int tid = threadIdx.x;
    if (tid < DIMS) {
        float sc = __uint_as_float(scale_u[tid]);
        s_inv[tid] = (sc != 0.f) ? 1.f / sc : 0.f;  // divide_no_nan
    }
    __syncthreads();

    // 2 queries per thread in named v4f registers
    v4f q0_0, q0_1, q0_2, q0_3, q0_4, q0_5, q0_6;
    v4f q1_0, q1_1, q1_2, q1_3, q1_4, q1_5, q1_6;
    float qn0, qn1;
    LOADQ(tid,      q0_0, q0_1, q0_2, q0_3, q0_4, q0_5, q0_6, qn0);
    LOADQ(tid + T1, q1_0, q1_1, q1_2, q1_3, q1_4, q1_5, q1_6, qn1);

    float bd00 = 3.4e38f, bd01 = 3.4e38f, bd02 = 3.4e38f;
    float bd10 = 3.4e38f, bd11 = 3.4e38f, bd12 = 3.4e38f;
    int   bi00 = 0, bi01 = 0, bi02 = 0;
    int   bi10 = 0, bi11 = 0, bi12 = 0;

    int p0 = blockIdx.x * PPB;
    int pe = min(p0 + PPB, N_TRAIN);

    for (int base = p0; base < pe; base += SPTS) {
        int cnt = min(SPTS, pe - base);
        int tot = cnt * DIMS;
        const float* src = train + (size_t)base * DIMS; // contiguous rows -> flat coalesced copy
        for (int i = tid; i < tot; i += T1) {
            int row = i / DIMS;
            int col = i - row * DIMS;
            s_pts[row * 28 + col] = src[i] * s_inv[col];
        }
        __syncthreads();
        for (int p = tid; p < cnt; p += T1) {
            float s2 = 0.f;
#pragma unroll
            for (int d = 0; d < DIMS; ++d) { float v = s_pts[p * 28 + d]; s2 = fmaf(v, v, s2); }
            s_pts[p * 28 + 27] = s2;
        }
        __syncthreads();

        for (int p = 0; p < cnt; ++p) {
            const v4f* rr = (const v4f*)(s_pts + p * 28); // broadcast: all lanes same addr
            v4f x0 = rr[0], x1 = rr[1], x2 = rr[2], x3 = rr[3];
            v4f x4 = rr[4], x5 = rr[5], x6 = rr[6];
            float xn = x6.w;
            int gidx = base + p;

            v4f a = (v4f){q0_0.x * x0.x, q0_0.y * x0.y, q0_0.z * x0.z, q0_0.w * x0.w};
            FMA4(a, q0_1, x1); FMA4(a, q0_2, x2); FMA4(a, q0_3, x3);
            FMA4(a, q0_4, x4); FMA4(a, q0_5, x5); FMA4(a, q0_6, x6); // q0_6.w==0 kills xn slot
            float dot0 = (a.x + a.y) + (a.z + a.w);
            float d2_0 = fmaf(-2.f, dot0, qn0 + xn);

            v4f b = (v4f){q1_0.x * x0.x, q1_0.y * x0.y, q1_0.z * x0.z, q1_0.w * x0.w};
            FMA4(b, q1_1, x1); FMA4(b, q1_2, x2); FMA4(b, q1_3, x3);
            FMA4(b, q1_4, x4); FMA4(b, q1_5, x5); FMA4(b, q1_6, x6);
            float dot1 = (b.x + b.y) + (b.z + b.w);
            float d2_1 = fmaf(-2.f, dot1, qn1 + xn);

            TOP3(d2_0, gidx, bd00, bd01, bd02, bi00, bi01, bi02);
            TOP3(d2_1, gidx, bd10, bd11, bd12, bi10, bi11, bi12);
        }
        __syncthreads();
    }

    int g = blockIdx.x;
    {
        size_t off = (size_t)tid * (G1 * KNN) + (size_t)g * KNN;
        cand_d[off + 0] = bd00; cand_d[off + 1] = bd01; cand_d[off + 2] = bd02;
        cand_i[off + 0] = bi00; cand_i[off + 1] = bi01; cand_i[off + 2] = bi02;
    }
    {
        size_t off = (size_t)(tid + T1) * (G1 * KNN) + (size_t)g * KNN;
        cand_d[off + 0] = bd10; cand_d[off + 1] = bd11; cand_d[off + 2] = bd12;
        cand_i[off + 0] = bi10; cand_i[off + 1] = bi11; cand_i[off + 2] = bi12;
    }
}

// lexicographic (d, i) insert into sorted triple — matches top_k tie-breaking
__device__ inline void insert3(float d, int i, float* bd, int* bi) {
    if (d < bd[2] || (d == bd[2] && i < bi[2])) {
        if (d < bd[1] || (d == bd[1] && i < bi[1])) {
            bd[2] = bd[1]; bi[2] = bi[1];
            if (d < bd[0] || (d == bd[0] && i < bi[0])) {
                bd[1] = bd[0]; bi[1] = bi[0];
                bd[0] = d; bi[0] = i;
            } else { bd[1] = d; bi[1] = i; }
        } else { bd[2] = d; bi[2] = i; }
    }
}

// ---------------- pass 2: merge + vote ----------------
__global__ __launch_bounds__(T2) void k_pass2(const float* __restrict__ cand_d,
                                              const int* __restrict__ cand_i,
                                              const float* __restrict__ labels,
                                              float* __restrict__ out) {
    int q = blockIdx.x, tid = threadIdx.x;
    const float* cd = cand_d + (size_t)q * (G1 * KNN);
    const int*   ci = cand_i + (size_t)q * (G1 * KNN);
    float bd[KNN] = {3.4e38f, 3.4e38f, 3.4e38f};
    int   bi[KNN] = {0x7fffffff, 0x7fffffff, 0x7fffffff};
    for (int c = tid; c < G1 * KNN; c += T2) insert3(cd[c], ci[c], bd, bi);

    __shared__ float sd[T2][KNN];
    __shared__ int   si[T2][KNN];
#pragma unroll
    for (int k = 0; k < KNN; ++k) { sd[tid][k] = bd[k]; si[tid][k] = bi[k]; }
    __syncthreads();
    for (int s = T2 / 2; s > 0; s >>= 1) {
        if (tid < s) {
#pragma unroll
            for (int k = 0; k < KNN; ++k) insert3(sd[tid + s][k], si[tid + s][k], bd, bi);
#pragma unroll
            for (int k = 0; k < KNN; ++k) { sd[tid][k] = bd[k]; si[tid][k] = bi[k]; }
        }
        __syncthreads();
    }

    if (tid == 0) {
        float kd[KNN];
#pragma unroll
        for (int k = 0; k < KNN; ++k) kd[k] = sqrtf(fmaxf(bd[k], 0.f));
        float lab[KNN][NCLS];
#pragma unroll
        for (int k = 0; k < KNN; ++k) {
            const float* lr = labels + (size_t)bi[k] * NCLS;
#pragma unroll
            for (int c = 0; c < NCLS; ++c) lab[k][c] = lr[c];
        }
        float votes[NCLS];
#pragma unroll
        for (int c = 0; c < NCLS; ++c) votes[c] = 0.f;
#pragma unroll
        for (int k = 0; k < KNN; ++k) {
            float ks = (kd[k] == 0.f) ? 1.f : kd[k];
#pragma unroll
            for (int c = 0; c < NCLS; ++c) votes[c] += lab[k][c] / ks;
        }
        int best = 0; float bv = votes[0];
#pragma unroll
        for (int c = 1; c < NCLS; ++c) { if (votes[c] > bv) { bv = votes[c]; best = c; } }
        bool zero_hit = (kd[0] == 0.f);
#pragma unroll
        for (int k = 0; k < KNN; ++k) out[(size_t)q * KNN + k] = kd[k];
        float* ro = out + (size_t)BQ * KNN + (size_t)q * NCLS;
#pragma unroll
        for (int c = 0; c < NCLS; ++c)
            ro[c] = zero_hit ? lab[0][c] : ((c == best) ? 1.f : 0.f);
    }
}

extern "C" void kernel_launch(void* const* d_in, const int* in_sizes, int n_in,
                              void* d_out, int out_size, void* d_ws, size_t ws_size,
                              hipStream_t stream) {
    const float* query  = (const float*)d_in[0];
    const float* train  = (const float*)d_in[1];
    const float* labels = (const float*)d_in[2];
    float* out = (float*)d_out;

    // ws layout:
    //   [0)       scale_u: 32 u32 (128 B)
    //   [128)     cand_d: 512*1024*3 f32 (6291456 B)
    //   [6291584) cand_i: 512*1024*3 i32 (6291456 B)   total ~12.6 MB
    char* ws = (char*)d_ws;
    unsigned* scale_u = (unsigned*)ws;
    float* cand_d = (float*)(ws + 128);
    int*   cand_i = (int*)(ws + 6291584);

    hipMemsetAsync(ws, 0, 128, stream);  // zero scale accumulators
    k_scale<<<SB, 256, 0, stream>>>(train, scale_u);
    k_pass1<<<G1, T1, 0, stream>>>(train, query, scale_u, cand_d, cand_i);
    k_pass2<<<BQ, T2, 0, stream>>>(cand_d, cand_i, labels, out);
}

// Round 6
// 263.466 us; speedup vs baseline: 1.4890x; 1.4890x over previous
//
#include <hip/hip_runtime.h>
#include <math.h>

typedef _Float16 h8 __attribute__((ext_vector_type(8)));
typedef float    f4v __attribute__((ext_vector_type(4)));

#define N_TRAIN 400000
#define DIMS    27
#define BQ      512
#define NCLS    11
#define KNN     3
#define NB      500            // pass-1 blocks
#define TPB     512            // pass-1 threads (8 waves)
#define PTS_BLK 800            // points per block (exact: 500*800 = 400000)
#define PTS_SUP 160            // points per super-tile (10 ptiles)
#define NSUP    5              // super-tiles per block
#define NPT     10             // ptiles per super-tile
#define REC     2624           // LDS record: hi 16*80 + lo 16*80 + xn 16*4
#define RAWF    4320           // floats per super-tile (160*27)
#define NC      (NB * KNN)     // candidates per query (1500)
#define SB      512            // k_scale blocks
#define SROWS   128

// ---------------- scale = max(|train|, axis=0), coalesced via LDS staging ----------------
__global__ __launch_bounds__(256) void k_scale(const float* __restrict__ train,
                                               unsigned* __restrict__ scale_u) {
    __shared__ float st[SROWS * DIMS];
    __shared__ float sp[243];
    int tid = threadIdx.x;
    int rpb = (N_TRAIN + SB - 1) / SB;
    int r0 = blockIdx.x * rpb;
    int r1 = min(r0 + rpb, N_TRAIN);
    int c  = tid % DIMS;
    int rr = tid / DIMS;
    float m = 0.f;
    for (int base = r0; base < r1; base += SROWS) {
        int cnt = min(SROWS, r1 - base);
        int tot = cnt * DIMS;
        const float* src = train + (size_t)base * DIMS;
        for (int i = tid; i < tot; i += 256) st[i] = src[i];
        __syncthreads();
        if (tid < 243) {
            for (int r = rr; r < cnt; r += 9)
                m = fmaxf(m, fabsf(st[r * DIMS + c]));
        }
        __syncthreads();
    }
    if (tid < 243) sp[tid] = m;
    __syncthreads();
    if (tid < DIMS) {
        float v = 0.f;
#pragma unroll
        for (int g = 0; g < 9; ++g) v = fmaxf(v, sp[g * DIMS + tid]);
        atomicMax(&scale_u[tid], __float_as_uint(v));
    }
}

// ---------------- query prep: split-f16 B-fragments + qn ----------------
__global__ __launch_bounds__(TPB) void k_qprep(const float* __restrict__ query,
                                               const unsigned* __restrict__ scale_u,
                                               _Float16* __restrict__ Qhi,
                                               _Float16* __restrict__ Qlo,
                                               float* __restrict__ qn) {
    int q = threadIdx.x;
    if (q >= BQ) return;
    const float* r = query + (size_t)q * DIMS;
    float s2 = 0.f;
#pragma unroll
    for (int d = 0; d < 32; ++d) {
        float xs = 0.f;
        if (d < DIMS) {
            float sc = __uint_as_float(scale_u[d]);
            float inv = (sc != 0.f) ? 1.f / sc : 0.f;   // divide_no_nan
            xs = r[d] * inv;
            s2 = fmaf(xs, xs, s2);
        }
        _Float16 hi = (_Float16)xs;
        _Float16 lo = (_Float16)(xs - (float)hi);
        Qhi[q * 32 + d] = hi;
        Qlo[q * 32 + d] = lo;
    }
    qn[q] = s2;
}

// strict-< top3 insert (scan-order tie-break: earlier index wins)
#define TOP3(D2, GI, B0, B1, B2, I0, I1, I2) \
    if ((D2) < B2) { \
        if ((D2) < B1) { \
            B2 = B1; I2 = I1; \
            if ((D2) < B0) { B1 = B0; I1 = I0; B0 = (D2); I0 = (GI); } \
            else { B1 = (D2); I1 = (GI); } \
        } else { B2 = (D2); I2 = (GI); } \
    }

// lexicographic (d, i) insert into sorted triple — matches top_k tie-breaking
__device__ inline void insert3(float d, int i, float* bd, int* bi) {
    if (d < bd[2] || (d == bd[2] && i < bi[2])) {
        if (d < bd[1] || (d == bd[1] && i < bi[1])) {
            bd[2] = bd[1]; bi[2] = bi[1];
            if (d < bd[0] || (d == bd[0] && i < bi[0])) {
                bd[1] = bd[0]; bi[1] = bi[0];
                bd[0] = d; bi[0] = i;
            } else { bd[1] = d; bi[1] = i; }
        } else { bd[2] = d; bi[2] = i; }
    }
}

// lexicographic insert into sorted 8 (registers, fully unrolled)
__device__ inline void ins8(float d, int i, float* bd, int* bi) {
    if (!(d < bd[7] || (d == bd[7] && i < bi[7]))) return;
#pragma unroll
    for (int k = 7; k >= 1; --k) {
        if (d < bd[k - 1] || (d == bd[k - 1] && i < bi[k - 1])) {
            bd[k] = bd[k - 1]; bi[k] = bi[k - 1];
        } else { bd[k] = d; bi[k] = i; return; }
    }
    bd[0] = d; bi[0] = i;
}

// ---------------- pass 1: split-f16 MFMA distances + per-lane top-3 ----------------
// A-frag: point m = lane&15, k = quad*8+j.  B-frag: query n = lane&15, k = quad*8+j.
// C/D: col = lane&15 = query, row = quad*4+reg = point (dtype-independent, m89).
__global__ __launch_bounds__(TPB)
void k_pass1(const float* __restrict__ train,
             const unsigned* __restrict__ scale_u,
             const _Float16* __restrict__ Qhi,
             const _Float16* __restrict__ Qlo,
             const float* __restrict__ qn,
             float* __restrict__ cand_d,
             int* __restrict__ cand_i) {
    __shared__ float s_inv[32];
    __shared__ __align__(16) float raw[2][RAWF];
    __shared__ __align__(16) unsigned char conv[NPT * REC];

    int tid = threadIdx.x;
    if (tid < DIMS) {
        float sc = __uint_as_float(scale_u[tid]);
        s_inv[tid] = (sc != 0.f) ? 1.f / sc : 0.f;
    }
    // zero conv once: pad k-slots (27..39) stay zero forever
    for (int i = tid; i < NPT * REC / 4; i += TPB) ((unsigned*)conv)[i] = 0u;

    int lane = tid & 63, w = tid >> 6;
    int l15 = lane & 15, quad = lane >> 4;

    h8 bhi[4], blo[4];
    float qn4[4];
#pragma unroll
    for (int j = 0; j < 4; ++j) {
        int qt = w * 4 + j;
        size_t e = (size_t)(qt * 16 + l15) * 32 + quad * 8;
        bhi[j] = *(const h8*)(Qhi + e);
        blo[j] = *(const h8*)(Qlo + e);
        qn4[j] = qn[qt * 16 + l15];
    }

    float bd[4][KNN];
    int   bi[4][KNN];
#pragma unroll
    for (int j = 0; j < 4; ++j)
#pragma unroll
        for (int k = 0; k < KNN; ++k) { bd[j][k] = 3.4e38f; bi[j][k] = 0; }

    int p0 = blockIdx.x * PTS_BLK;
    const uint4* gsrc = (const uint4*)(train + (size_t)p0 * DIMS); // p0*108 % 16 == 0

    uint4 ra, rb, rc;
    ra = gsrc[tid]; rb = gsrc[tid + 512];
    if (tid < 56) rc = gsrc[tid + 1024];

    for (int s = 0; s < NSUP; ++s) {
        uint4* dst = (uint4*)raw[s & 1];
        dst[tid] = ra; dst[tid + 512] = rb;
        if (tid < 56) dst[tid + 1024] = rc;
        if (s + 1 < NSUP) {
            const uint4* nsrc = gsrc + (size_t)(s + 1) * (RAWF / 4);
            ra = nsrc[tid]; rb = nsrc[tid + 512];
            if (tid < 56) rc = nsrc[tid + 1024];
        }
        __syncthreads();   // raw[s] staged; compute(s-1) done -> conv reusable

        const float* rw = raw[s & 1];
        for (int e = tid; e < PTS_SUP * DIMS; e += TPB) {
            int p = e / DIMS, d = e - p * DIMS;
            float xs = rw[e] * s_inv[d];
            _Float16 hi = (_Float16)xs;
            _Float16 lo = (_Float16)(xs - (float)hi);
            unsigned char* rec = conv + (p >> 4) * REC + (p & 15) * 80 + d * 2;
            *(_Float16*)rec = hi;
            *(_Float16*)(rec + 1280) = lo;
        }
        if (tid < PTS_SUP) {
            const float* rr = rw + tid * DIMS;
            float s2 = 0.f;
#pragma unroll
            for (int d = 0; d < DIMS; ++d) { float v = rr[d] * s_inv[d]; s2 = fmaf(v, v, s2); }
            *(float*)(conv + (tid >> 4) * REC + 2560 + (tid & 15) * 4) = s2;
        }
        __syncthreads();   // conv ready

        for (int t = 0; t < NPT; ++t) {
            const unsigned char* rec = conv + t * REC;
            h8  ahi = *(const h8*)(rec + l15 * 80 + quad * 16);
            h8  alo = *(const h8*)(rec + 1280 + l15 * 80 + quad * 16);
            f4v xn4 = *(const f4v*)(rec + 2560 + quad * 16);
            int pb = p0 + (s * NPT + t) * 16 + quad * 4;
#pragma unroll
            for (int j = 0; j < 4; ++j) {
                f4v acc = {0.f, 0.f, 0.f, 0.f};
                acc = __builtin_amdgcn_mfma_f32_16x16x32_f16(alo, bhi[j], acc, 0, 0, 0);
                acc = __builtin_amdgcn_mfma_f32_16x16x32_f16(ahi, blo[j], acc, 0, 0, 0);
                acc = __builtin_amdgcn_mfma_f32_16x16x32_f16(ahi, bhi[j], acc, 0, 0, 0);
#pragma unroll
                for (int r = 0; r < 4; ++r) {
                    float d2 = fmaf(-2.f, acc[r], qn4[j] + xn4[r]);
                    int gi = pb + r;
                    TOP3(d2, gi, bd[j][0], bd[j][1], bd[j][2], bi[j][0], bi[j][1], bi[j][2]);
                }
            }
        }
    }

    // cross-quad merge: lanes {l15, l15+16, l15+32, l15+48} hold the same queries
    // over disjoint point subsets -> butterfly merge of sorted triples.
#pragma unroll
    for (int j = 0; j < 4; ++j) {
#pragma unroll
        for (int step = 16; step <= 32; step <<= 1) {
            float od[KNN]; int oi[KNN];
#pragma unroll
            for (int k = 0; k < KNN; ++k) {
                od[k] = __shfl_xor(bd[j][k], step, 64);
                oi[k] = __shfl_xor(bi[j][k], step, 64);
            }
#pragma unroll
            for (int k = 0; k < KNN; ++k) insert3(od[k], oi[k], bd[j], bi[j]);
        }
    }

    if (quad == 0) {
        int g = blockIdx.x;
#pragma unroll
        for (int j = 0; j < 4; ++j) {
            int qq = (w * 4 + j) * 16 + l15;
            size_t off = (size_t)qq * NC + (size_t)g * KNN;
#pragma unroll
            for (int k = 0; k < KNN; ++k) { cand_d[off + k] = bd[j][k]; cand_i[off + k] = bi[j][k]; }
        }
    }
}

// ---------------- pass 2: approx top-8 merge -> exact f32 refine -> vote ----------------
// One wave per query. The exact refine reproduces R1's fmaf chains bitwise, so the
// final top-3/vote are immune to the split-f16 approximation (only needs the true
// top-3 to land in the approx top-8).
__global__ __launch_bounds__(64) void k_pass2(const float* __restrict__ cand_d,
                                              const int* __restrict__ cand_i,
                                              const float* __restrict__ train,
                                              const float* __restrict__ query,
                                              const unsigned* __restrict__ scale_u,
                                              const float* __restrict__ labels,
                                              float* __restrict__ out) {
    int q = blockIdx.x, lane = threadIdx.x;
    const float* cd = cand_d + (size_t)q * NC;
    const int*   ci = cand_i + (size_t)q * NC;

    float d8[8]; int i8v[8];
#pragma unroll
    for (int k = 0; k < 8; ++k) { d8[k] = 3.4e38f; i8v[k] = 0x7fffffff; }
    for (int c = lane; c < NC; c += 64) ins8(cd[c], ci[c], d8, i8v);

#pragma unroll
    for (int step = 1; step < 64; step <<= 1) {
        float od[8]; int oi[8];
#pragma unroll
        for (int k = 0; k < 8; ++k) {
            od[k] = __shfl_xor(d8[k], step, 64);
            oi[k] = __shfl_xor(i8v[k], step, 64);
        }
#pragma unroll
        for (int k = 0; k < 8; ++k) ins8(od[k], oi[k], d8, i8v);
    }
    // all lanes now hold the identical global approx top-8 (sorted)

    // exact f32 scaled query + qn (same op order as R1 k_qprep: absmax 0.0)
    float inv[DIMS], qs_[DIMS], qn_ = 0.f;
#pragma unroll
    for (int d = 0; d < DIMS; ++d) {
        float sc = __uint_as_float(scale_u[d]);
        float iv = (sc != 0.f) ? 1.f / sc : 0.f;
        float v = query[(size_t)q * DIMS + d] * iv;
        inv[d] = iv; qs_[d] = v;
        qn_ = fmaf(v, v, qn_);
    }

    int myi = 0x7fffffff;
#pragma unroll
    for (int k = 0; k < 8; ++k) if (lane == k) myi = i8v[k];
    float myd2 = 3.4e38f;
    if (lane < 8) {
        const float* r = train + (size_t)myi * DIMS;
        float xnv = 0.f, dot = 0.f;
#pragma unroll
        for (int d = 0; d < DIMS; ++d) {
            float v = r[d] * inv[d];            // same as R1 staging scale
            xnv = fmaf(v, v, xnv);
            dot = fmaf(qs_[d], v, dot);
        }
        myd2 = fmaf(-2.f, dot, qn_ + xnv);      // identical to R1 formula
    }

    // gather exact (d2, idx) and take lexicographic top-3
    float bd[KNN] = {3.4e38f, 3.4e38f, 3.4e38f};
    int   bi[KNN] = {0x7fffffff, 0x7fffffff, 0x7fffffff};
#pragma unroll
    for (int k = 0; k < 8; ++k) {
        float dk = __shfl(myd2, k, 64);
        int   ik = __shfl(myi, k, 64);
        insert3(dk, ik, bd, bi);
    }

    if (lane == 0) {
        float kd[KNN];
#pragma unroll
        for (int k = 0; k < KNN; ++k) kd[k] = sqrtf(fmaxf(bd[k], 0.f));
        float lab[KNN][NCLS];
#pragma unroll
        for (int k = 0; k < KNN; ++k) {
            const float* lr = labels + (size_t)bi[k] * NCLS;
#pragma unroll
            for (int c = 0; c < NCLS; ++c) lab[k][c] = lr[c];
        }
        float votes[NCLS];
#pragma unroll
        for (int c = 0; c < NCLS; ++c) votes[c] = 0.f;
#pragma unroll
        for (int k = 0; k < KNN; ++k) {
            float ks = (kd[k] == 0.f) ? 1.f : kd[k];
#pragma unroll
            for (int c = 0; c < NCLS; ++c) votes[c] += lab[k][c] / ks;
        }
        int best = 0; float bv = votes[0];
#pragma unroll
        for (int c = 1; c < NCLS; ++c) { if (votes[c] > bv) { bv = votes[c]; best = c; } }
        bool zero_hit = (kd[0] == 0.f);
#pragma unroll
        for (int k = 0; k < KNN; ++k) out[(size_t)q * KNN + k] = kd[k];
        float* ro = out + (size_t)BQ * KNN + (size_t)q * NCLS;
#pragma unroll
        for (int c = 0; c < NCLS; ++c)
            ro[c] = zero_hit ? lab[0][c] : ((c == best) ? 1.f : 0.f);
    }
}

extern "C" void kernel_launch(void* const* d_in, const int* in_sizes, int n_in,
                              void* d_out, int out_size, void* d_ws, size_t ws_size,
                              hipStream_t stream) {
    const float* query  = (const float*)d_in[0];
    const float* train  = (const float*)d_in[1];
    const float* labels = (const float*)d_in[2];
    float* out = (float*)d_out;

    // ws layout:
    //   [0)       scale_u: 32 u32
    //   [128)     Qhi: 512*32 f16 (32768 B)
    //   [32896)   Qlo: 512*32 f16 (32768 B)
    //   [65664)   qn:  512 f32 (2048 B)
    //   [67712)   cand_d: 512*1500 f32 (3072000 B)
    //   [3139712) cand_i: 512*1500 i32 (3072000 B)   total ~6.2 MB
    char* ws = (char*)d_ws;
    unsigned*  scale_u = (unsigned*)ws;
    _Float16*  Qhi = (_Float16*)(ws + 128);
    _Float16*  Qlo = (_Float16*)(ws + 32896);
    float*     qn  = (float*)(ws + 65664);
    float*     cand_d = (float*)(ws + 67712);
    int*       cand_i = (int*)(ws + 3139712);

    hipMemsetAsync(ws, 0, 128, stream);  // zero scale accumulators
    k_scale<<<SB, 256, 0, stream>>>(train, scale_u);
    k_qprep<<<1, TPB, 0, stream>>>(query, scale_u, Qhi, Qlo, qn);
    k_pass1<<<NB, TPB, 0, stream>>>(train, scale_u, Qhi, Qlo, qn, cand_d, cand_i);
    k_pass2<<<BQ, 64, 0, stream>>>(cand_d, cand_i, train, query, scale_u, labels, out);
}

// Round 7
// 235.391 us; speedup vs baseline: 1.6666x; 1.1193x over previous
//
#include <hip/hip_runtime.h>
#include <math.h>

typedef _Float16 h8 __attribute__((ext_vector_type(8)));
typedef float    f4v __attribute__((ext_vector_type(4)));

#define N_TRAIN 400000
#define DIMS    27
#define BQ      512
#define NCLS    11
#define KNN     3
#define NB      500            // pass-1 blocks
#define TPB     512            // pass-1 threads (8 waves)
#define PTS_BLK 800            // points per block (500*800 = 400000 exact)
#define PTS_SUP 160            // points per super-tile (10 ptiles)
#define NSUP    5
#define NPT     10
#define RAWF    4320           // floats per super-tile (160*27)
#define TILE_B  2048           // conv bytes per ptile: hi 1024 + lo 1024
#define NC      (NB * KNN)     // candidates per query (1500)
#define SB      512            // k_scale blocks
#define RPB     784            // rows per k_scale block (784*27 divisible by 4)
#define SROWS   128

// ---------------- scale = max(|train|, axis=0), uint4-staged ----------------
__global__ __launch_bounds__(256) void k_scale(const float* __restrict__ train,
                                               unsigned* __restrict__ scale_u) {
    __shared__ float st[SROWS * DIMS];   // 3456 floats
    __shared__ float sp[243];
    int tid = threadIdx.x;
    int r0 = blockIdx.x * RPB;
    int r1 = min(r0 + RPB, N_TRAIN);
    int c  = tid % DIMS;
    int rr = tid / DIMS;
    float m = 0.f;
    for (int base = r0; base < r1; base += SROWS) {
        int cnt = min(SROWS, r1 - base);     // always a multiple of 4 here
        int tot4 = (cnt * DIMS) >> 2;
        const uint4* src4 = (const uint4*)(train + (size_t)base * DIMS); // 16B aligned
        uint4* st4 = (uint4*)st;
        for (int i = tid; i < tot4; i += 256) st4[i] = src4[i];
        __syncthreads();
        if (tid < 243) {
            for (int r = rr; r < cnt; r += 9)
                m = fmaxf(m, fabsf(st[r * DIMS + c]));
        }
        __syncthreads();
    }
    if (tid < 243) sp[tid] = m;
    __syncthreads();
    if (tid < DIMS) {
        float v = 0.f;
#pragma unroll
        for (int g = 0; g < 9; ++g) v = fmaxf(v, sp[g * DIMS + tid]);
        atomicMax(&scale_u[tid], __float_as_uint(v)); // values >= 0: uint order == float order
    }
}

// ---------------- query prep: split-f16 B-fragments, k=27 slot = {1,0} ----------------
__global__ __launch_bounds__(TPB) void k_qprep(const float* __restrict__ query,
                                               const unsigned* __restrict__ scale_u,
                                               _Float16* __restrict__ Qhi,
                                               _Float16* __restrict__ Qlo) {
    int q = threadIdx.x;
    if (q >= BQ) return;
    const float* r = query + (size_t)q * DIMS;
#pragma unroll
    for (int d = 0; d < 32; ++d) {
        _Float16 hi = (_Float16)0.f, lo = (_Float16)0.f;
        if (d < DIMS) {
            float sc = __uint_as_float(scale_u[d]);
            float inv = (sc != 0.f) ? 1.f / sc : 0.f;   // divide_no_nan
            float xs = r[d] * inv;
            hi = (_Float16)xs;
            lo = (_Float16)(xs - (float)hi);
        } else if (d == 27) {
            hi = (_Float16)1.f;   // multiplies A's -xn/2 hi+lo slots
        }
        Qhi[q * 32 + d] = hi;
        Qlo[q * 32 + d] = lo;
    }
}

// branchless rolling top-2 (largest acc; strict > keeps earlier index on ties)
#define TOP2(A, GI, B0, B1, I0, I1) do { \
    bool c0_ = (A) > (B0); \
    bool c1_ = (A) > (B1); \
    B1 = c0_ ? (B0) : (c1_ ? (A) : (B1)); \
    I1 = c0_ ? (I0) : (c1_ ? (GI) : (I1)); \
    B0 = c0_ ? (A) : (B0); \
    I0 = c0_ ? (GI) : (I0); \
} while (0)

// lexicographic (key, idx) insert into ascending sorted triple — matches top_k ties
__device__ __forceinline__ void insert3(float d, int i, float* bd, int* bi) {
    if (d < bd[2] || (d == bd[2] && i < bi[2])) {
        if (d < bd[1] || (d == bd[1] && i < bi[1])) {
            bd[2] = bd[1]; bi[2] = bi[1];
            if (d < bd[0] || (d == bd[0] && i < bi[0])) {
                bd[1] = bd[0]; bi[1] = bi[0];
                bd[0] = d; bi[0] = i;
            } else { bd[1] = d; bi[1] = i; }
        } else { bd[2] = d; bi[2] = i; }
    }
}

// lexicographic insert into sorted 8
__device__ __forceinline__ void ins8(float d, int i, float* bd, int* bi) {
    if (!(d < bd[7] || (d == bd[7] && i < bi[7]))) return;
#pragma unroll
    for (int k = 7; k >= 1; --k) {
        if (d < bd[k - 1] || (d == bd[k - 1] && i < bi[k - 1])) {
            bd[k] = bd[k - 1]; bi[k] = bi[k - 1];
        } else { bd[k] = d; bi[k] = i; return; }
    }
    bd[0] = d; bi[0] = i;
}

__device__ __forceinline__ void stage16(const float* g, float* l) {
    __builtin_amdgcn_global_load_lds((const __attribute__((address_space(1))) void*)g,
                                     (__attribute__((address_space(3))) void*)l, 16, 0, 0);
}

// ---------------- pass 1: split-f16 MFMA (xn folded) + branchless per-lane top-2 ----------------
// A-frag: point m = lane&15, k = quad*8+j ; linear LDS layout -> A-read addr = lane*16 (conflict-free).
// acc = dot - xn/2 ; top-3 smallest d2 == top-3 largest acc (qn constant per query).
__global__ __attribute__((amdgpu_flat_work_group_size(TPB, TPB)))
__attribute__((amdgpu_waves_per_eu(4, 4)))
void k_pass1(const float* __restrict__ train,
             const unsigned* __restrict__ scale_u,
             const _Float16* __restrict__ Qhi,
             const _Float16* __restrict__ Qlo,
             float* __restrict__ cand_d,
             int* __restrict__ cand_i) {
    __shared__ float s_inv[32];
    __shared__ __align__(16) float raw[2][RAWF];                 // 34560 B
    __shared__ __align__(16) unsigned char conv[NPT * TILE_B];   // 20480 B

    int tid = threadIdx.x;
    if (tid < 32) {
        float sc = __uint_as_float(scale_u[tid]);       // 0 for d>=27 (memset)
        s_inv[tid] = (sc != 0.f) ? 1.f / sc : 0.f;
    }
    int lane = tid & 63, w = tid >> 6;
    int l15 = lane & 15, quad = lane >> 4;

    h8 bhi[4], blo[4];
#pragma unroll
    for (int j = 0; j < 4; ++j) {
        int qt = w * 4 + j;
        size_t e = (size_t)(qt * 16 + l15) * 32 + quad * 8;
        bhi[j] = *(const h8*)(Qhi + e);
        blo[j] = *(const h8*)(Qlo + e);
    }

    float b0[4], b1[4];
    int   i0[4], i1[4];
#pragma unroll
    for (int j = 0; j < 4; ++j) { b0[j] = -3.4e38f; b1[j] = -3.4e38f; i0[j] = 0x7fffffff; i1[j] = 0x7fffffff; }

    int p0 = blockIdx.x * PTS_BLK;
    const float* gsup = train + (size_t)p0 * DIMS;   // 16B aligned (800*108 % 16 == 0)

    // async stage super-tile 0
    {
        const float* gp = gsup; float* lp = raw[0];
        stage16(gp + tid * 4, lp + tid * 4);
        stage16(gp + 2048 + tid * 4, lp + 2048 + tid * 4);
        if (tid < 56) stage16(gp + 4096 + tid * 4, lp + 4096 + tid * 4);
    }

    for (int s = 0; s < NSUP; ++s) {
        __syncthreads();   // drains vmcnt -> raw[s] ready; conv free (compute s-1 done)

        // ---- convert: task = (point p, kblock gq of 8 dims) ----
        const float* rw = raw[s & 1];
#pragma unroll
        for (int pass = 0; pass < 2; ++pass) {
            int task = tid + pass * TPB;
            if (task < PTS_SUP * 4) {
                int p = task >> 2, gq = task & 3;
                float x[8]; float part = 0.f;
#pragma unroll
                for (int i = 0; i < 8; ++i) {
                    int d = gq * 8 + i;
                    int dc = d < DIMS ? d : (DIMS - 1);     // clamp; s_inv[d>=27]=0 zeroes value
                    float v = rw[p * DIMS + dc] * s_inv[d];
                    x[i] = v;
                    part = fmaf(v, v, part);
                }
                part += __shfl_xor(part, 1, 64);
                part += __shfl_xor(part, 2, 64);            // all 4 kblock-lanes hold xn
                h8 hv, lv;
#pragma unroll
                for (int i = 0; i < 8; ++i) {
                    _Float16 h = (_Float16)x[i];
                    hv[i] = h;
                    lv[i] = (_Float16)(x[i] - (float)h);
                }
                if (gq == 3) {                              // slot i=3 is k=27: -xn/2 split
                    float tt = -0.5f * part;
                    _Float16 th = (_Float16)tt;
                    hv[3] = th;
                    lv[3] = (_Float16)(tt - (float)th);
                }
                unsigned char* dstb = conv + (p >> 4) * TILE_B + gq * 256 + (p & 15) * 16;
                *(h8*)dstb = hv;
                *(h8*)(dstb + 1024) = lv;
            }
        }
        __syncthreads();   // conv ready (no vm ops outstanding here)

        if (s + 1 < NSUP) {   // async stage next super-tile; flies during compute
            const float* gp = gsup + (size_t)(s + 1) * RAWF;
            float* lp = raw[(s + 1) & 1];
            stage16(gp + tid * 4, lp + tid * 4);
            stage16(gp + 2048 + tid * 4, lp + 2048 + tid * 4);
            if (tid < 56) stage16(gp + 4096 + tid * 4, lp + 4096 + tid * 4);
        }

        // ---- compute: 10 ptiles x 4 query-tiles x 3 MFMA ----
        for (int t = 0; t < NPT; ++t) {
            const unsigned char* basep = conv + t * TILE_B;
            h8 ahi = *(const h8*)(basep + lane * 16);           // lane-linear: conflict-free
            h8 alo = *(const h8*)(basep + 1024 + lane * 16);
            int gbase = p0 + (s * NPT + t) * 16 + quad * 4;
#pragma unroll
            for (int j = 0; j < 4; ++j) {
                f4v acc = {0.f, 0.f, 0.f, 0.f};
                acc = __builtin_amdgcn_mfma_f32_16x16x32_f16(alo, bhi[j], acc, 0, 0, 0);
                acc = __builtin_amdgcn_mfma_f32_16x16x32_f16(ahi, blo[j], acc, 0, 0, 0);
                acc = __builtin_amdgcn_mfma_f32_16x16x32_f16(ahi, bhi[j], acc, 0, 0, 0);
#pragma unroll
                for (int r = 0; r < 4; ++r)
                    TOP2(acc[r], gbase + r, b0[j], b1[j], i0[j], i1[j]);
            }
        }
    }

    // cross-quad merge (4 disjoint point subsets per query) -> block top-3, keys = -acc
    int g = blockIdx.x;
#pragma unroll
    for (int j = 0; j < 4; ++j) {
        float kk[3] = {-b0[j], -b1[j], 3.4e38f};
        int   ii[3] = {i0[j], i1[j], 0x7fffffff};
#pragma unroll
        for (int step = 16; step <= 32; step <<= 1) {
            float od[3]; int oi[3];
#pragma unroll
            for (int k = 0; k < 3; ++k) {
                od[k] = __shfl_xor(kk[k], step, 64);
                oi[k] = __shfl_xor(ii[k], step, 64);
            }
#pragma unroll
            for (int k = 0; k < 3; ++k) insert3(od[k], oi[k], kk, ii);
        }
        if (quad == 0) {
            int qq = (w * 4 + j) * 16 + l15;
            size_t off = (size_t)qq * NC + (size_t)g * KNN;
#pragma unroll
            for (int k = 0; k < KNN; ++k) { cand_d[off + k] = kk[k]; cand_i[off + k] = ii[k]; }
        }
    }
}

// ---------------- pass 2: approx top-8 merge -> exact f32 refine -> vote ----------------
__global__ __launch_bounds__(64) void k_pass2(const float* __restrict__ cand_d,
                                              const int* __restrict__ cand_i,
                                              const float* __restrict__ train,
                                              const float* __restrict__ query,
                                              const unsigned* __restrict__ scale_u,
                                              const float* __restrict__ labels,
                                              float* __restrict__ out) {
    int q = blockIdx.x, lane = threadIdx.x;
    const float* cd = cand_d + (size_t)q * NC;
    const int*   ci = cand_i + (size_t)q * NC;

    float d8[8]; int i8v[8];
#pragma unroll
    for (int k = 0; k < 8; ++k) { d8[k] = 3.4e38f; i8v[k] = 0x7fffffff; }
    for (int c = lane; c < NC; c += 64) ins8(cd[c], ci[c], d8, i8v);

#pragma unroll
    for (int step = 1; step < 64; step <<= 1) {
        float od[8]; int oi[8];
#pragma unroll
        for (int k = 0; k < 8; ++k) {
            od[k] = __shfl_xor(d8[k], step, 64);
            oi[k] = __shfl_xor(i8v[k], step, 64);
        }
#pragma unroll
        for (int k = 0; k < 8; ++k) ins8(od[k], oi[k], d8, i8v);
    }
    // all lanes hold identical global approx top-8

    // exact f32 scaled query + qn (same op order as the verified R1 path)
    float inv[DIMS], qs_[DIMS], qn_ = 0.f;
#pragma unroll
    for (int d = 0; d < DIMS; ++d) {
        float sc = __uint_as_float(scale_u[d]);
        float iv = (sc != 0.f) ? 1.f / sc : 0.f;
        float v = query[(size_t)q * DIMS + d] * iv;
        inv[d] = iv; qs_[d] = v;
        qn_ = fmaf(v, v, qn_);
    }

    int myi = 0x7fffffff;
#pragma unroll
    for (int k = 0; k < 8; ++k) if (lane == k) myi = i8v[k];
    float myd2 = 3.4e38f;
    if (lane < 8) {
        const float* r = train + (size_t)myi * DIMS;
        float xnv = 0.f, dot = 0.f;
#pragma unroll
        for (int d = 0; d < DIMS; ++d) {
            float v = r[d] * inv[d];
            xnv = fmaf(v, v, xnv);
            dot = fmaf(qs_[d], v, dot);
        }
        myd2 = fmaf(-2.f, dot, qn_ + xnv);
    }

    float bd[KNN] = {3.4e38f, 3.4e38f, 3.4e38f};
    int   bi[KNN] = {0x7fffffff, 0x7fffffff, 0x7fffffff};
#pragma unroll
    for (int k = 0; k < 8; ++k) {
        float dk = __shfl(myd2, k, 64);
        int   ik = __shfl(myi, k, 64);
        insert3(dk, ik, bd, bi);
    }

    if (lane == 0) {
        float kd[KNN];
#pragma unroll
        for (int k = 0; k < KNN; ++k) kd[k] = sqrtf(fmaxf(bd[k], 0.f));
        float lab[KNN][NCLS];
#pragma unroll
        for (int k = 0; k < KNN; ++k) {
            const float* lr = labels + (size_t)bi[k] * NCLS;
#pragma unroll
            for (int c = 0; c < NCLS; ++c) lab[k][c] = lr[c];
        }
        float votes[NCLS];
#pragma unroll
        for (int c = 0; c < NCLS; ++c) votes[c] = 0.f;
#pragma unroll
        for (int k = 0; k < KNN; ++k) {
            float ks = (kd[k] == 0.f) ? 1.f : kd[k];
#pragma unroll
            for (int c = 0; c < NCLS; ++c) votes[c] += lab[k][c] / ks;
        }
        int best = 0; float bv = votes[0];
#pragma unroll
        for (int c = 1; c < NCLS; ++c) { if (votes[c] > bv) { bv = votes[c]; best = c; } }
        bool zero_hit = (kd[0] == 0.f);
#pragma unroll
        for (int k = 0; k < KNN; ++k) out[(size_t)q * KNN + k] = kd[k];
        float* ro = out + (size_t)BQ * KNN + (size_t)q * NCLS;
#pragma unroll
        for (int c = 0; c < NCLS; ++c)
            ro[c] = zero_hit ? lab[0][c] : ((c == best) ? 1.f : 0.f);
    }
}

extern "C" void kernel_launch(void* const* d_in, const int* in_sizes, int n_in,
                              void* d_out, int out_size, void* d_ws, size_t ws_size,
                              hipStream_t stream) {
    const float* query  = (const float*)d_in[0];
    const float* train  = (const float*)d_in[1];
    const float* labels = (const float*)d_in[2];
    float* out = (float*)d_out;

    // ws layout:
    //   [0)       scale_u: 32 u32 (128 B)
    //   [128)     Qhi: 512*32 f16 (32768 B)
    //   [32896)   Qlo: 512*32 f16 (32768 B)
    //   [65664)   cand_d: 512*1500 f32 (3072000 B)
    //   [3137664) cand_i: 512*1500 i32 (3072000 B)   total ~6.2 MB
    char* ws = (char*)d_ws;
    unsigned*  scale_u = (unsigned*)ws;
    _Float16*  Qhi = (_Float16*)(ws + 128);
    _Float16*  Qlo = (_Float16*)(ws + 32896);
    float*     cand_d = (float*)(ws + 65664);
    int*       cand_i = (int*)(ws + 3137664);

    hipMemsetAsync(ws, 0, 128, stream);  // zero scale accumulators
    k_scale<<<SB, 256, 0, stream>>>(train, scale_u);
    k_qprep<<<1, TPB, 0, stream>>>(query, scale_u, Qhi, Qlo);
    k_pass1<<<NB, TPB, 0, stream>>>(train, scale_u, Qhi, Qlo, cand_d, cand_i);
    k_pass2<<<BQ, 64, 0, stream>>>(cand_d, cand_i, train, query, scale_u, labels, out);
}